// Round 7
// baseline (181.820 us; speedup 1.0000x reference)
//
#include <hip/hip_runtime.h>

// OneDilate: out[b,c,i,j] = 50 - 0.5 * sum_{10x10 clamped window} x
// Persistent-block, double-buffered LDS pipeline (T3 minimum 2-phase).
//  Grid = 256 blocks (1/CU). Each block owns (band bx, image-group ig) and
//  loops 12 images: STAGE(next image tile -> buf^1 via global_load_lds w=16)
//  is issued BEFORE compute(buf), then one counted drain (asm vmcnt(0) +
//  s_barrier) per tile. Stage latency hides under ~5000cy of compute; no
//  block launch/retire dead time (round 6: stage->full-drain->compute->exit
//  gave VALU 36% / HBM 31% / all-idle-together, 60us).
//  Phase B (verbatim from round 6, passed): 4 output rows x 4 cols/thread,
//  4 aligned float4 LDS reads/row, direct accumulation.
// LDS layout linear (global_load_lds wave-uniform base + lane*16, m104).

#define IMG 512
#define OUTW 511
#define KS 10
#define MEAN 4
#define SUBB 16                  // output rows per tile
#define TS (SUBB + KS - 1)       // 25 streamed rows
#define ROWF4 (IMG / 4)          // 128 float4 per row
#define NF4 (TS * ROWF4)         // 3200 float4 = 50 KiB per buffer
#define TILEF (TS * IMG)         // 12800 floats per buffer
#define NTHREADS 512
#define NBANDS (IMG / SUBB)      // 32
#define NIG 8                    // image groups
#define TPB 12                   // images (tiles) per block: 8*12 = 96

__global__ __launch_bounds__(NTHREADS) void onedilate_kernel(
    const float* __restrict__ x, float* __restrict__ out)
{
    __shared__ float smemf[2 * TILEF];   // 102400 B: two 25x512 buffers

    // 256 blocks; HW round-robins dispatch over 8 XCDs, so pick work such
    // that XCD x receives all 32 bands of image-group x (halo rows between
    // band-adjacent blocks stay in one XCD's L2).
    const int lin = blockIdx.y * NBANDS + blockIdx.x;   // 0..255
    const int swz = (lin & 7) * 32 + (lin >> 3);
    const int bx  = swz & (NBANDS - 1);  // band
    const int ig  = swz >> 5;            // image group

    const int tid = threadIdx.x;
    const int rb  = bx * SUBB;           // first output row of this band

    // Per-thread constants (phase B).
    const int j  = tid & 127;            // col group: output cols 4j..4j+3
    const int rg = tid >> 7;             // row group 0..3 (4 rows each)
    const int cbase = 4 * j;
    const int bl0 = max(cbase - 4, 0);        // only j=0 OOB-low
    const int bl2 = min(cbase + 4, IMG - 4);  // only j=127 OOB-high
    const int bl3 = min(cbase + 8, IMG - 4);  // j=126,127 OOB-high
    const bool lo0 = (cbase - 4 < 0);
    const bool hi2 = (cbase + 4 > IMG - 4);
    const bool hi3 = (cbase + 8 > IMG - 4);

    // idx -> (streamed row r = idx>>7, col-group c4 = idx&127); row clamped.
    // LDS byte offset = buf*TILEF*4 + idx*16: linear in tid (HW lane*16).
#define STAGE1(buf_, xim_, idx_)                                           \
    {                                                                      \
        const int r_  = (idx_) >> 7;                                       \
        const int c4_ = (idx_) & (ROWF4 - 1);                              \
        const int ri_ = min(max(rb - MEAN + r_, 0), IMG - 1);              \
        __builtin_amdgcn_global_load_lds(                                  \
            (const __attribute__((address_space(1))) void*)                \
                ((xim_) + (size_t)ri_ * IMG + c4_ * 4),                    \
            (__attribute__((address_space(3))) void*)                      \
                (smemf + (buf_) * TILEF + (idx_) * 4),                     \
            16, 0, 0);                                                     \
    }
#define STAGE(buf_, xim_)                                                  \
    {                                                                      \
        _Pragma("unroll")                                                  \
        for (int k = 0; k < 6; ++k) STAGE1(buf_, xim_, k * NTHREADS + tid) \
        if (tid < (NF4 - 6 * NTHREADS)) STAGE1(buf_, xim_, 6 * NTHREADS + tid) \
    }
#define DRAIN_BARRIER()                                                    \
    {                                                                      \
        asm volatile("s_waitcnt vmcnt(0)" ::: "memory");                   \
        __builtin_amdgcn_sched_barrier(0);                                 \
        __builtin_amdgcn_s_barrier();                                      \
    }

    // Prologue: stage tile 0 into buffer 0.
    {
        const float* xim0 = x + (size_t)(ig * TPB) * (IMG * IMG);
        STAGE(0, xim0)
    }
    DRAIN_BARRIER()

    int cur = 0;
#pragma unroll 1
    for (int t = 0; t < TPB; ++t) {
        // Issue next tile's loads into the other buffer (overlaps compute).
        if (t + 1 < TPB) {
            const float* xnext = x + (size_t)(ig * TPB + t + 1) * (IMG * IMG);
            STAGE(cur ^ 1, xnext)
        }

        // ---------------- compute from buf[cur] ----------------
        const float* sf = smemf + cur * TILEF;
        float4 a0 = make_float4(0.f, 0.f, 0.f, 0.f);
        float4 a1 = a0, a2 = a0, a3 = a0;

#define ACC4(A) { A.x += H.x; A.y += H.y; A.z += H.z; A.w += H.w; }
#pragma unroll
        for (int sl = 0; sl < 13; ++sl) {
            const int s = rg * 4 + sl;    // local streamed row in [0,24]
            const float* rp = sf + s * IMG;
            float4 v0 = *(const float4*)(rp + bl0);
            float4 v1 = *(const float4*)(rp + cbase);
            float4 v2 = *(const float4*)(rp + bl2);
            float4 v3 = *(const float4*)(rp + bl3);
            if (lo0) v0 = make_float4(v0.x, v0.x, v0.x, v0.x);  // col 0 repl
            if (hi2) v2 = make_float4(v2.w, v2.w, v2.w, v2.w);  // col 511 repl
            const float w12 = hi3 ? v3.w : v3.x;                // min(4j+8,511)

            // Horizontal 10-sums: tree sum + parallel sliding diffs.
            const float S = ((v0.x + v0.y) + (v0.z + v0.w))
                          + ((v1.x + v1.y) + (v1.z + v1.w))
                          + (v2.x + v2.y);
            const float d1  = v2.z - v0.x;
            const float d2  = v2.w - v0.y;
            const float d3  = w12  - v0.z;
            const float d12 = d1 + d2;
            float4 H;
            H.x = S;
            H.y = S + d1;
            H.z = S + d12;
            H.w = S + (d12 + d3);

            // Vertical windows: output ro sums sl in [ro, ro+9].
            if (sl <= 9)             ACC4(a0)
            if (sl >= 1 && sl <= 10) ACC4(a1)
            if (sl >= 2 && sl <= 11) ACC4(a2)
            if (sl >= 3)             ACC4(a3)
        }
#undef ACC4

        float* oim = out + (size_t)(ig * TPB + t) * (OUTW * OUTW);
        const int i0 = rb + rg * 4;
#define STORE(ro, A)                                                       \
        { const int i = i0 + (ro);                                         \
          if (i < OUTW) {                                                  \
              float* op = oim + (size_t)i * OUTW + cbase;                  \
              op[0] = fmaf(A.x, -0.5f, 50.0f);                             \
              op[1] = fmaf(A.y, -0.5f, 50.0f);                             \
              op[2] = fmaf(A.z, -0.5f, 50.0f);                             \
              if (cbase + 3 < OUTW) op[3] = fmaf(A.w, -0.5f, 50.0f);       \
          } }
        STORE(0, a0)
        STORE(1, a1)
        STORE(2, a2)
        STORE(3, a3)
#undef STORE

        // Next tile's loads landed during compute; ensure before next iter
        // (and before anyone re-stages into buf[cur]).
        DRAIN_BARRIER()
        cur ^= 1;
    }
#undef STAGE
#undef STAGE1
#undef DRAIN_BARRIER
}

extern "C" void kernel_launch(void* const* d_in, const int* in_sizes, int n_in,
                              void* d_out, int out_size, void* d_ws, size_t ws_size,
                              hipStream_t stream) {
    const float* x = (const float*)d_in[0];
    float* out = (float*)d_out;

    dim3 block(NTHREADS, 1, 1);
    dim3 grid(NBANDS, NIG, 1);   // 32 x 8 = 256 blocks (1 per CU)
    onedilate_kernel<<<grid, block, 0, stream>>>(x, out);
}

// Round 8
// 180.081 us; speedup vs baseline: 1.0097x; 1.0097x over previous
//
#include <hip/hip_runtime.h>

// OneDilate: out[b,c,i,j] = 50 - 0.5 * sum_{10x10 clamped window} x
// Separable two-pass LDS kernel (10x10 box = V10 then H10, clamps separable).
//  1024-thread blocks, SUBB=32 output rows/tile, 1 block/CU, 16 waves.
//  LDS: T (41x512 raw tile, 84KB) + V (32x512 vertical sums, 64KB) = 149.5KB.
//  Per tile: B1 vertical running-sums T->V (13 ds_read_b128/thread);
//            barrier; STAGE(next tile -> T, global_load_lds w=16, T is dead);
//            B2 horizontal 10-sums V->out (16 ds_read/thread, proven H-sum
//            code from rounds 4-7); barrier (drains stage vmcnt).
//  Round-7 lesson: fused phase-B re-read each tile 8.3x from LDS (~50% of
//  time) + VALU 29%. Separable cuts LDS/output 3.6x and VALU 2.5x; HBM
//  write (~98MB, 15.5us) + fetch becomes the floor (~23us).

#define IMG 512
#define OUTW 511
#define KS 10
#define MEAN 4
#define SUBB 32                  // output rows per tile
#define TS (SUBB + KS - 1)       // 41 staged rows
#define ROWF4 (IMG / 4)          // 128 float4 per row
#define TF4 (TS * ROWF4)         // 5248 float4 staged per tile
#define TILEF (TS * IMG)         // 20992 floats (T buffer)
#define VF (SUBB * IMG)          // 16384 floats (V buffer)
#define SMEM_BYTES ((TILEF + VF) * 4)   // 149504 B
#define NTHREADS 1024
#define NBANDS (IMG / SUBB)      // 16
#define TPB 6                    // images per block: 256 blocks x 6 = 1536 tiles

__device__ __forceinline__ float4 f4add(float4 a, float4 b) {
    return make_float4(a.x + b.x, a.y + b.y, a.z + b.z, a.w + b.w);
}
__device__ __forceinline__ float4 f4slide(float4 v, float4 add, float4 sub) {
    return make_float4(v.x + add.x - sub.x, v.y + add.y - sub.y,
                       v.z + add.z - sub.z, v.w + add.w - sub.w);
}

__global__ __launch_bounds__(NTHREADS) void onedilate_kernel(
    const float* __restrict__ x, float* __restrict__ out)
{
    extern __shared__ float smem[];
    float* Tb = smem;            // 41 x 512 raw rows
    float* Vb = smem + TILEF;    // 32 x 512 vertical 10-sums

    // XCD x (dispatch round-robin over blockIdx) owns images 12x..12x+11:
    // all 16 bands of one image are processed concurrently on one XCD ->
    // ~2MB working set fits its 4MB L2 (shared halo rows hit L2).
    const int lin   = blockIdx.x;        // 0..255
    const int xcd   = lin & 7;
    const int slot  = lin >> 3;          // 0..31
    const int band  = slot & (NBANDS - 1);
    const int ihalf = slot >> 4;         // 0..1
    const int img0  = xcd * 12 + ihalf * TPB;
    const int rb    = band * SUBB;       // first output row of this band

    const int tid = threadIdx.x;
    const int jc  = tid & (ROWF4 - 1);   // float4 col group 0..127
    const int rg  = tid >> 7;            // row group 0..7 (4 rows each)
    const int vr0 = rg * 4;

    // Horizontal-pass constants (identical to proven phase-B clamps).
    const int cbase = 4 * jc;
    const int bl0 = max(cbase - 4, 0);        // only jc=0 OOB-low
    const int bl2 = min(cbase + 4, IMG - 4);  // only jc=127 OOB-high
    const int bl3 = min(cbase + 8, IMG - 4);  // jc=126,127 OOB-high
    const bool lo0 = (cbase - 4 < 0);
    const bool hi2 = (cbase + 4 > IMG - 4);
    const bool hi3 = (cbase + 8 > IMG - 4);

    // Stage: idx -> (row r = idx>>7, colgroup c4 = idx&127); row clamped.
    // LDS byte offset = idx*16, linear in tid (HW wave-base + lane*16, m104).
#define STAGE1(xim_, idx_)                                                 \
    {                                                                      \
        const int r_  = (idx_) >> 7;                                       \
        const int c4_ = (idx_) & (ROWF4 - 1);                              \
        const int ri_ = min(max(rb - MEAN + r_, 0), IMG - 1);              \
        __builtin_amdgcn_global_load_lds(                                  \
            (const __attribute__((address_space(1))) void*)                \
                ((xim_) + (size_t)ri_ * IMG + c4_ * 4),                    \
            (__attribute__((address_space(3))) void*)(Tb + (idx_) * 4),    \
            16, 0, 0);                                                     \
    }
#define STAGE(xim_)                                                        \
    {                                                                      \
        _Pragma("unroll")                                                  \
        for (int k = 0; k < 5; ++k) STAGE1(xim_, k * NTHREADS + tid)       \
        if (tid < (TF4 - 5 * NTHREADS)) STAGE1(xim_, 5 * NTHREADS + tid)   \
    }

    // Prologue: stage tile 0.
    STAGE(x + (size_t)img0 * (IMG * IMG))
    __syncthreads();

#pragma unroll 1
    for (int t = 0; t < TPB; ++t) {
        // ---------- B1: vertical 10-sums T -> V (running sum) ----------
        // Thread (jc, rg): V rows vr0..vr0+3 from T rows vr0..vr0+12.
        {
            const float4* Tv = (const float4*)Tb;
            float4* Vv = (float4*)Vb;
            const float4 t0  = Tv[(vr0 + 0) * ROWF4 + jc];
            const float4 t1  = Tv[(vr0 + 1) * ROWF4 + jc];
            const float4 t2  = Tv[(vr0 + 2) * ROWF4 + jc];
            const float4 t3  = Tv[(vr0 + 3) * ROWF4 + jc];
            const float4 t4  = Tv[(vr0 + 4) * ROWF4 + jc];
            const float4 t5  = Tv[(vr0 + 5) * ROWF4 + jc];
            const float4 t6  = Tv[(vr0 + 6) * ROWF4 + jc];
            const float4 t7  = Tv[(vr0 + 7) * ROWF4 + jc];
            const float4 t8  = Tv[(vr0 + 8) * ROWF4 + jc];
            const float4 t9  = Tv[(vr0 + 9) * ROWF4 + jc];
            const float4 t10 = Tv[(vr0 + 10) * ROWF4 + jc];
            const float4 t11 = Tv[(vr0 + 11) * ROWF4 + jc];
            const float4 t12 = Tv[(vr0 + 12) * ROWF4 + jc];
            float4 v = f4add(f4add(f4add(f4add(t0, t1), f4add(t2, t3)),
                                   f4add(f4add(t4, t5), f4add(t6, t7))),
                             f4add(t8, t9));
            Vv[(vr0 + 0) * ROWF4 + jc] = v;
            v = f4slide(v, t10, t0);
            Vv[(vr0 + 1) * ROWF4 + jc] = v;
            v = f4slide(v, t11, t1);
            Vv[(vr0 + 2) * ROWF4 + jc] = v;
            v = f4slide(v, t12, t2);
            Vv[(vr0 + 3) * ROWF4 + jc] = v;
        }
        __syncthreads();   // V complete; all T reads done -> T is dead

        // Stage next tile into T; DMA overlaps B2 below (drained at the
        // end-of-iter barrier).
        if (t + 1 < TPB) STAGE(x + (size_t)(img0 + t + 1) * (IMG * IMG))

        // ---------- B2: horizontal 10-sums V -> out ----------
        {
            float* oim = out + (size_t)(img0 + t) * (OUTW * OUTW);
#pragma unroll
            for (int k = 0; k < 4; ++k) {
                const int r = vr0 + k;
                const float* rp = Vb + r * IMG;
                float4 v0 = *(const float4*)(rp + bl0);
                float4 v1 = *(const float4*)(rp + cbase);
                float4 v2 = *(const float4*)(rp + bl2);
                float4 v3 = *(const float4*)(rp + bl3);
                if (lo0) v0 = make_float4(v0.x, v0.x, v0.x, v0.x);  // col 0
                if (hi2) v2 = make_float4(v2.w, v2.w, v2.w, v2.w);  // col 511
                const float w12 = hi3 ? v3.w : v3.x;       // col min(4jc+8,511)

                const float S = ((v0.x + v0.y) + (v0.z + v0.w))
                              + ((v1.x + v1.y) + (v1.z + v1.w))
                              + (v2.x + v2.y);
                const float d1  = v2.z - v0.x;
                const float d2  = v2.w - v0.y;
                const float d3  = w12  - v0.z;
                const float d12 = d1 + d2;

                const int i = rb + r;
                if (i < OUTW) {
                    float* op = oim + (size_t)i * OUTW + cbase;
                    op[0] = fmaf(S, -0.5f, 50.0f);
                    op[1] = fmaf(S + d1, -0.5f, 50.0f);
                    op[2] = fmaf(S + d12, -0.5f, 50.0f);
                    if (cbase + 3 < OUTW)
                        op[3] = fmaf(S + (d12 + d3), -0.5f, 50.0f);
                }
            }
        }
        // Drains each wave's stage vmcnt, then barrier: next B1 reads T
        // safely; V protected from next overwrite.
        __syncthreads();
    }
#undef STAGE
#undef STAGE1
}

extern "C" void kernel_launch(void* const* d_in, const int* in_sizes, int n_in,
                              void* d_out, int out_size, void* d_ws, size_t ws_size,
                              hipStream_t stream) {
    const float* x = (const float*)d_in[0];
    float* out = (float*)d_out;

    static bool attr_set = false;
    if (!attr_set) {
        hipFuncSetAttribute((const void*)onedilate_kernel,
                            hipFuncAttributeMaxDynamicSharedMemorySize,
                            SMEM_BYTES);
        attr_set = true;
    }

    dim3 block(NTHREADS, 1, 1);
    dim3 grid(256, 1, 1);        // 1 block per CU; 6 tiles each
    onedilate_kernel<<<grid, block, SMEM_BYTES, stream>>>(x, out);
}